// Round 1
// baseline (138.069 us; speedup 1.0000x reference)
//
#include <hip/hip_runtime.h>
#include <math.h>

// Problem constants (match reference)
#define B_ 2
#define T_ 2048
#define M_ 768
#define R_ 64
#define S_ 16
#define NC 64              // number of t-chunks for the 3-phase scan
#define CL (T_ / NC)       // 32 steps per chunk
#define LOG_EPS_F (-23.025850929940457f)

// --------------------------------------------------------------------------
// Kernel 1: dt[bt][m] = clip(softplus(delta[bt][:] . dt_w[m][:] + dt_b[m]))
// Tiled 64x64 GEMM-like, K=64, LDS-staged with transpose.
// --------------------------------------------------------------------------
__global__ __launch_bounds__(256) void dt_kernel(
    const float* __restrict__ delta,   // [B*T][R]
    const float* __restrict__ dt_w,    // [M][R]
    const float* __restrict__ dt_b,    // [M]
    float* __restrict__ dt_out)        // [B*T][M]
{
  __shared__ float ds_d[R_][68];   // [r][t]  (pad 68 keeps 16B alignment, breaks worst conflicts)
  __shared__ float ds_w[R_][68];   // [r][m]
  const int tid = threadIdx.x;
  const int m0  = blockIdx.x * 64;
  const int bt0 = blockIdx.y * 64;

  // stage: coalesced float4 loads, transposed scatter into LDS
  #pragma unroll
  for (int k = 0; k < 4; ++k) {
    int idx = tid + k * 256;            // 0..1023
    int rq = idx & 15;                  // which float4 along r
    int x  = idx >> 4;                  // row (t or m), 0..63
    float4 dv = *reinterpret_cast<const float4*>(&delta[(size_t)(bt0 + x) * R_ + rq * 4]);
    ds_d[rq * 4 + 0][x] = dv.x; ds_d[rq * 4 + 1][x] = dv.y;
    ds_d[rq * 4 + 2][x] = dv.z; ds_d[rq * 4 + 3][x] = dv.w;
    float4 wv = *reinterpret_cast<const float4*>(&dt_w[(size_t)(m0 + x) * R_ + rq * 4]);
    ds_w[rq * 4 + 0][x] = wv.x; ds_w[rq * 4 + 1][x] = wv.y;
    ds_w[rq * 4 + 2][x] = wv.z; ds_w[rq * 4 + 3][x] = wv.w;
  }
  __syncthreads();

  const int mq = tid & 15, tq = tid >> 4;
  const int ml = mq * 4, tl = tq * 4;
  float acc[4][4] = {};
  #pragma unroll 4
  for (int r = 0; r < R_; ++r) {
    float4 dv = *reinterpret_cast<const float4*>(&ds_d[r][tl]);  // broadcast within 16-lane group
    float4 wv = *reinterpret_cast<const float4*>(&ds_w[r][ml]);
    float d[4] = {dv.x, dv.y, dv.z, dv.w};
    float w[4] = {wv.x, wv.y, wv.z, wv.w};
    #pragma unroll
    for (int i = 0; i < 4; ++i)
      #pragma unroll
      for (int j = 0; j < 4; ++j)
        acc[i][j] = fmaf(d[i], w[j], acc[i][j]);
  }

  float4 bb = *reinterpret_cast<const float4*>(&dt_b[m0 + ml]);
  float bv[4] = {bb.x, bb.y, bb.z, bb.w};
  #pragma unroll
  for (int i = 0; i < 4; ++i) {
    float4 o;
    float* op = &o.x;
    #pragma unroll
    for (int j = 0; j < 4; ++j) {
      float x = acc[i][j] + bv[j];
      float sp = (x > 20.f) ? x : log1pf(__expf(x));   // softplus
      op[j] = fminf(fmaxf(sp, 1e-6f), 10.f);           // clip
    }
    *reinterpret_cast<float4*>(&dt_out[(size_t)(bt0 + tl + i) * M_ + m0 + ml]) = o;
  }
}

// --------------------------------------------------------------------------
// Kernel 2: Bm[bt][s] = u[bt][:] . B_w[s][:] ; Cm likewise. K=768 reduction.
// Block = 8 t x 32 s2 (s2<16 -> B, else C). u row broadcast across lanes.
// --------------------------------------------------------------------------
__global__ __launch_bounds__(256) void bc_kernel(
    const float* __restrict__ u,     // [B*T][M]
    const float* __restrict__ B_w,   // [S][M]
    const float* __restrict__ C_w,   // [S][M]
    float* __restrict__ Bm,          // [B*T][S]
    float* __restrict__ Cm)          // [B*T][S]
{
  const int tid = threadIdx.x;
  const int s2 = tid & 31;
  const int tl = tid >> 5;                 // 0..7
  const int bt = blockIdx.x * 8 + tl;
  const float* w = (s2 < 16) ? &B_w[(size_t)s2 * M_] : &C_w[(size_t)(s2 - 16) * M_];
  const float* ur = &u[(size_t)bt * M_];
  float acc = 0.f;
  #pragma unroll 8
  for (int m = 0; m < M_; m += 4) {
    float4 uv = *reinterpret_cast<const float4*>(&ur[m]);
    float4 wv = *reinterpret_cast<const float4*>(&w[m]);
    acc = fmaf(uv.x, wv.x, acc);
    acc = fmaf(uv.y, wv.y, acc);
    acc = fmaf(uv.z, wv.z, acc);
    acc = fmaf(uv.w, wv.w, acc);
  }
  if (s2 < 16) Bm[(size_t)bt * S_ + s2] = acc;
  else         Cm[(size_t)bt * S_ + (s2 - 16)] = acc;
}

// --------------------------------------------------------------------------
// Kernels 3 & 5: chunk-local scan. Thread owns (b, m, chunk), 16 s-states in
// registers. PHASE 1: h_in=0, record per-chunk decay product + local h_end.
// PHASE 3: h_in=carry, produce y and final output.
// --------------------------------------------------------------------------
template <int PHASE>
__global__ __launch_bounds__(256) void scan_kernel(
    const float* __restrict__ dt_ws,   // [B*T][M]
    const float* __restrict__ u,       // [B*T][M]
    const float* __restrict__ Bm,      // [B*T][S]
    const float* __restrict__ Cm,      // [B*T][S]
    const float* __restrict__ A_log,   // [S][M]
    const float* __restrict__ D,       // [M]
    float* __restrict__ Aprod,         // [B][NC][M][S]
    float* __restrict__ Hend,          // [B][NC][M][S]
    const float* __restrict__ carry,   // [B][NC][M][S]
    float* __restrict__ out)           // [B*T][M]
{
  const int tid = threadIdx.x;
  const int m = blockIdx.x * 256 + tid;   // 0..767
  const int c = blockIdx.y;               // chunk
  const int b = blockIdx.z;

  float Acol[S_], h[S_], P[S_];
  #pragma unroll
  for (int s = 0; s < S_; ++s) {
    float a = -expf(A_log[(size_t)s * M_ + m]);
    Acol[s] = fminf(fmaxf(a, -10.f), -1e-6f);   // clip(-exp(A_log), -10, -1e-6)
  }
  float Dm = 0.f;
  if constexpr (PHASE == 1) {
    #pragma unroll
    for (int s = 0; s < S_; ++s) { h[s] = 0.f; P[s] = 1.f; }
  } else {
    const size_t cb = (((size_t)b * NC + c) * M_ + m) * S_;
    #pragma unroll
    for (int s4 = 0; s4 < 4; ++s4) {
      float4 hv = *reinterpret_cast<const float4*>(&carry[cb + s4 * 4]);
      h[s4 * 4 + 0] = hv.x; h[s4 * 4 + 1] = hv.y;
      h[s4 * 4 + 2] = hv.z; h[s4 * 4 + 3] = hv.w;
    }
    Dm = D[m];
  }

  const int t0 = c * CL;
  for (int t = t0; t < t0 + CL; ++t) {
    const size_t gi  = ((size_t)b * T_ + t) * M_ + m;
    const size_t bti = ((size_t)b * T_ + t) * S_;
    const float dtv = dt_ws[gi];
    const float uv  = u[gi];
    const float du  = dtv * uv;
    float bmv[S_], cmv[S_];
    #pragma unroll
    for (int s4 = 0; s4 < 4; ++s4) {
      float4 v = *reinterpret_cast<const float4*>(&Bm[bti + s4 * 4]);  // uniform -> s_load
      bmv[s4 * 4 + 0] = v.x; bmv[s4 * 4 + 1] = v.y;
      bmv[s4 * 4 + 2] = v.z; bmv[s4 * 4 + 3] = v.w;
      if constexpr (PHASE == 3) {
        float4 cv = *reinterpret_cast<const float4*>(&Cm[bti + s4 * 4]);
        cmv[s4 * 4 + 0] = cv.x; cmv[s4 * 4 + 1] = cv.y;
        cmv[s4 * 4 + 2] = cv.z; cmv[s4 * 4 + 3] = cv.w;
      }
    }
    float y = 0.f;
    #pragma unroll
    for (int s = 0; s < S_; ++s) {
      float la = fmaxf(dtv * Acol[s], LOG_EPS_F);
      float e = __expf(la);
      h[s] = fmaf(e, h[s], du * bmv[s]);
      if constexpr (PHASE == 1) P[s] *= e;
      else y = fmaf(h[s], cmv[s], y);
    }
    if constexpr (PHASE == 3) {
      float o = y + uv * Dm;
      o = fminf(fmaxf(o, -1e4f), 1e4f);
      out[gi] = o;
    }
  }

  if constexpr (PHASE == 1) {
    const size_t sb = (((size_t)b * NC + c) * M_ + m) * S_;
    #pragma unroll
    for (int s4 = 0; s4 < 4; ++s4) {
      float4 pv = make_float4(P[s4 * 4 + 0], P[s4 * 4 + 1], P[s4 * 4 + 2], P[s4 * 4 + 3]);
      *reinterpret_cast<float4*>(&Aprod[sb + s4 * 4]) = pv;
      float4 hv = make_float4(h[s4 * 4 + 0], h[s4 * 4 + 1], h[s4 * 4 + 2], h[s4 * 4 + 3]);
      *reinterpret_cast<float4*>(&Hend[sb + s4 * 4]) = hv;
    }
  }
}

// --------------------------------------------------------------------------
// Kernel 4: combine chunk summaries into per-chunk input carries.
// carry[c] = h-state entering chunk c.
// --------------------------------------------------------------------------
__global__ __launch_bounds__(256) void carry_kernel(
    const float* __restrict__ Aprod, const float* __restrict__ Hend,
    float* __restrict__ carry)
{
  const int idx = blockIdx.x * 256 + threadIdx.x;  // over B*M*S = 24576
  const int b = idx / (M_ * S_);
  const int ms = idx - b * (M_ * S_);
  float h = 0.f;
  for (int c = 0; c < NC; ++c) {
    const size_t o = ((size_t)b * NC + c) * (M_ * S_) + ms;
    carry[o] = h;
    h = fmaf(Aprod[o], h, Hend[o]);
  }
}

// --------------------------------------------------------------------------
extern "C" void kernel_launch(void* const* d_in, const int* in_sizes, int n_in,
                              void* d_out, int out_size, void* d_ws, size_t ws_size,
                              hipStream_t stream)
{
  const float* u     = (const float*)d_in[0];
  const float* delta = (const float*)d_in[1];
  const float* dt_w  = (const float*)d_in[2];
  const float* dt_b  = (const float*)d_in[3];
  const float* A_log = (const float*)d_in[4];
  const float* B_w   = (const float*)d_in[5];
  const float* C_w   = (const float*)d_in[6];
  const float* D     = (const float*)d_in[7];
  float* out = (float*)d_out;
  float* ws  = (float*)d_ws;

  // Workspace layout (floats). Total = 7,995,392 floats (~32 MB).
  float* dt_ws = ws;                                   // B*T*M
  float* Bm    = dt_ws + (size_t)B_ * T_ * M_;         // B*T*S
  float* Cm    = Bm    + (size_t)B_ * T_ * S_;         // B*T*S
  float* Aprod = Cm    + (size_t)B_ * T_ * S_;         // B*NC*M*S
  float* Hend  = Aprod + (size_t)B_ * NC * M_ * S_;    // B*NC*M*S
  float* carry = Hend  + (size_t)B_ * NC * M_ * S_;    // B*NC*M*S

  dt_kernel<<<dim3(M_ / 64, (B_ * T_) / 64), 256, 0, stream>>>(delta, dt_w, dt_b, dt_ws);
  bc_kernel<<<dim3((B_ * T_) / 8), 256, 0, stream>>>(u, B_w, C_w, Bm, Cm);
  scan_kernel<1><<<dim3(M_ / 256, NC, B_), 256, 0, stream>>>(
      dt_ws, u, Bm, Cm, A_log, D, Aprod, Hend, nullptr, nullptr);
  carry_kernel<<<dim3((B_ * M_ * S_) / 256), 256, 0, stream>>>(Aprod, Hend, carry);
  scan_kernel<3><<<dim3(M_ / 256, NC, B_), 256, 0, stream>>>(
      dt_ws, u, Bm, Cm, A_log, D, Aprod, Hend, carry, out);
}